// Round 9
// baseline (106.628 us; speedup 1.0000x reference)
//
#include <hip/hip_runtime.h>
#include <math.h>

// NT-Xent (SimCLR) loss. B=4096, D=256, T=0.5.
// R9: 256x256 tiles (was 128x128). R5/R6/R8 (three different schedules) all
// landed ~38us -> sum-of-pipes-bound, not schedule-bound. 256^2 halves
// operand bytes/output: VMEM total 400->135 MB (the slow 64 B/cy pipe),
// LDS r+w ~same. m201-template regime: 512 thr / 8 waves (2x4 grid,
// 128x64/wave, acc[8][4]=128 AGPR), BK=64, A+B glds-staged double-buffered
// (128 KB LDS, 1 block/CU, 2 waves/SIMD), 4 K-steps, counted vmcnt(8)
// (8 glds/wave/step), 8 barriers total, setprio on MFMA clusters.
//   zbF layout (unchanged): rg = row>>4, s = k>>5:
//     offset_shorts = rg*4096 + s*512 + ((k>>3)&3)*128 + (row&15)*8 + (k&7)
// Rows scaled by sqrt(2/ln2): acc = 2*sim/ln2 -> epilogue exp2(acc);
// posv holds 2*sim/ln2; reduce weight = 2*ln2.

#define NROWS 8192
#define NHALF 4096
#define DIM   256
#define BMT   256
#define NCB   (NROWS / 128)           // denomP slot granularity (64 slots)
#define NCBT  (NROWS / BMT)           // 32 tile rows/cols
#define NTRIT (NCBT * (NCBT + 1) / 2) // 528 triangle tiles

typedef __attribute__((ext_vector_type(8))) short bf16x8;
typedef __attribute__((ext_vector_type(4))) float f32x4;

static __device__ __forceinline__ unsigned short f2bf(float x) {
  unsigned int u = __float_as_uint(x);
  unsigned int r = (u + 0x7FFFu + ((u >> 16) & 1u)) >> 16;
  return (unsigned short)r;
}

// ---------------- normalize -> fragment-native layout (also zeroes out[0])
__global__ __launch_bounds__(256) void normalize_kernel(
    const float* __restrict__ emb_i, const float* __restrict__ emb_j,
    unsigned short* __restrict__ zbF, float* __restrict__ out) {
  __shared__ unsigned short tile[16 * DIM];  // 8 KB
  if (blockIdx.x == 0 && threadIdx.x == 0) out[0] = 0.f;
  const int w = threadIdx.x >> 6, lane = threadIdx.x & 63;
  const int rg = blockIdx.x;
  #pragma unroll
  for (int rr = 0; rr < 4; ++rr) {
    const int m16 = w * 4 + rr;
    const int row = rg * 16 + m16;
    const float* src = (row < NHALF) ? (emb_i + (size_t)row * DIM)
                                     : (emb_j + (size_t)(row - NHALF) * DIM);
    float4 v = ((const float4*)src)[lane];
    float ss = v.x * v.x + v.y * v.y + v.z * v.z + v.w * v.w;
    #pragma unroll
    for (int off = 32; off; off >>= 1) ss += __shfl_down(ss, off, 64);
    float total = __shfl(ss, 0, 64);
    // sqrt(2/ln2): acc = 2*sim/ln2, so epilogue is exp2(acc) directly.
    float inv = 1.69870077f / fmaxf(sqrtf(total), 1e-12f);
    ushort4 o;
    o.x = f2bf(v.x * inv); o.y = f2bf(v.y * inv);
    o.z = f2bf(v.z * inv); o.w = f2bf(v.w * inv);
    // k = lane*4 -> s = lane>>3, quad = (lane>>1)&3, j = (lane&1)*4
    const int s = lane >> 3, quad = (lane >> 1) & 3, jj = (lane & 1) * 4;
    *(ushort4*)&tile[s * 512 + (quad * 16 + m16) * 8 + jj] = o;
  }
  __syncthreads();
  uint4* dst = (uint4*)(zbF + (size_t)rg * (16 * DIM));
  const uint4* srcT = (const uint4*)tile;
  dst[threadIdx.x] = srcT[threadIdx.x];
  dst[256 + threadIdx.x] = srcT[256 + threadIdx.x];
}

// ------------------------------------------------ MFMA GEMM + exp + sums
__global__ __launch_bounds__(512, 2) void denom_kernel(
    const unsigned short* __restrict__ zbF, float* __restrict__ denomP,
    float* __restrict__ posv) {
  __shared__ unsigned short As[2][32 * 512];  // 2 x 32 KB: 256 rows x K=64
  __shared__ unsigned short Bs[2][32 * 512];  // 2 x 32 KB
  __shared__ float rowpart[4][256];           // per-wc row partials (4 KB)
  __shared__ float colpart[2][256];           // per-wr col partials (2 KB)

  // XCD-aware bijective swizzle (528 % 8 == 0)
  int t = (blockIdx.x & 7) * (NTRIT / 8) + (blockIdx.x >> 3);
  int by = (int)((sqrtf(8.0f * (float)t + 1.0f) - 1.0f) * 0.5f);
  while ((by + 1) * (by + 2) / 2 <= t) ++by;
  while (by * (by + 1) / 2 > t) --by;
  int bx = t - by * (by + 1) / 2;

  const int tid = threadIdx.x;
  const int w = tid >> 6;           // 8 waves
  const int lane = tid & 63;
  const int wr = w >> 2, wc = w & 3;  // 2x4 wave grid; wave = 128x64 out
  const int quad = lane >> 4;
  const int m16 = lane & 15;
  const int row0 = bx * BMT;
  const int col0 = by * BMT;

  // frag-native panels: 16 rgs per 256-row panel, 8 K32-slices each.
  const unsigned short* gA = zbF + (size_t)(bx * 16) * 4096 + lane * 8;
  const unsigned short* gB = zbF + (size_t)(by * 16) * 4096 + lane * 8;

  f32x4 acc[8][4];
  #pragma unroll
  for (int i = 0; i < 8; ++i)
    #pragma unroll
    for (int j = 0; j < 4; ++j) {
      f32x4 z4 = {0.f, 0.f, 0.f, 0.f};
      acc[i][j] = z4;
    }

  // stage K-step kt (64 wide) into buffer b: 32 A-chunks + 32 B-chunks of
  // 1 KB; wave w takes chunks c = w*4..w*4+3 of each (8 glds/wave, uniform
  // LDS base per wave). chunk c -> rl = c>>1 (16-row group), s32 = c&1.
  auto stage = [&](int b, int kt) {
    #pragma unroll
    for (int cc = 0; cc < 4; ++cc) {
      const int c = w * 4 + cc;
      const size_t goff = (size_t)(c >> 1) * 4096 + (kt * 2 + (c & 1)) * 512;
      __builtin_amdgcn_global_load_lds(
          (const __attribute__((address_space(1))) unsigned int*)(gA + goff),
          (__attribute__((address_space(3))) unsigned int*)&As[b][c * 512],
          16, 0, 0);
      __builtin_amdgcn_global_load_lds(
          (const __attribute__((address_space(1))) unsigned int*)(gB + goff),
          (__attribute__((address_space(3))) unsigned int*)&Bs[b][c * 512],
          16, 0, 0);
    }
  };

  // compute K-step from buffer b: 2 K32-slices x (8 A-frags x 4 B-frags)
  auto compute = [&](int b) {
    #pragma unroll
    for (int s32 = 0; s32 < 2; ++s32) {
      bf16x8 af[8], bf[4];
      #pragma unroll
      for (int i = 0; i < 8; ++i)
        af[i] = *(const bf16x8*)
            &As[b][((wr * 8 + i) * 2 + s32) * 512 + lane * 8];
      #pragma unroll
      for (int j = 0; j < 4; ++j)
        bf[j] = *(const bf16x8*)
            &Bs[b][((wc * 4 + j) * 2 + s32) * 512 + lane * 8];
      __builtin_amdgcn_s_setprio(1);
      #pragma unroll
      for (int i = 0; i < 8; ++i)
        #pragma unroll
        for (int j = 0; j < 4; ++j)
          acc[i][j] = __builtin_amdgcn_mfma_f32_16x16x32_bf16(
              af[i], bf[j], acc[i][j], 0, 0, 0);
      __builtin_amdgcn_s_setprio(0);
    }
  };

  // counted-vmcnt 2-buffer pipeline over 4 K-steps (8 glds/wave/step):
  stage(0, 0);
  stage(1, 1);
  asm volatile("s_waitcnt vmcnt(8)" ::: "memory");  // step0 landed
  __builtin_amdgcn_s_barrier();
  asm volatile("" ::: "memory");
  compute(0);
  __builtin_amdgcn_s_barrier();                     // buf0 reads done
  asm volatile("" ::: "memory");
  stage(0, 2);
  asm volatile("s_waitcnt vmcnt(8)" ::: "memory");  // step1 landed
  __builtin_amdgcn_s_barrier();
  asm volatile("" ::: "memory");
  compute(1);
  __builtin_amdgcn_s_barrier();
  asm volatile("" ::: "memory");
  stage(1, 3);
  asm volatile("s_waitcnt vmcnt(8)" ::: "memory");  // step2 landed
  __builtin_amdgcn_s_barrier();
  asm volatile("" ::: "memory");
  compute(0);
  __builtin_amdgcn_s_barrier();
  asm volatile("" ::: "memory");
  asm volatile("s_waitcnt vmcnt(0)" ::: "memory");  // step3 landed
  __builtin_amdgcn_s_barrier();
  asm volatile("" ::: "memory");
  compute(1);

  // pos extraction: tiles with col0 == row0 + NHALF (by == bx+16).
  if (col0 - row0 == NHALF) {
    #pragma unroll
    for (int i = 0; i < 8; ++i)
      #pragma unroll
      for (int j = 0; j < 4; ++j) {
        int gcol = col0 + wc * 64 + j * 16 + m16;
        #pragma unroll
        for (int r = 0; r < 4; ++r) {
          int grow = row0 + wr * 128 + i * 16 + quad * 4 + r;
          if (gcol - grow == NHALF) posv[grow] = acc[i][j][r];
        }
      }
  }

  // Epilogue: e = exp2(acc) = exp(2*sim). Diagonal tiles (bx==by, 32 of
  // 528) pay the grow==gcol compare; off-diagonal tiles skip it.
  float rs[8][4];
  float cs[4] = {0.f, 0.f, 0.f, 0.f};
  #pragma unroll
  for (int i = 0; i < 8; ++i)
    #pragma unroll
    for (int r = 0; r < 4; ++r) rs[i][r] = 0.f;

  if (bx != by) {
    #pragma unroll
    for (int i = 0; i < 8; ++i)
      #pragma unroll
      for (int j = 0; j < 4; ++j)
        #pragma unroll
        for (int r = 0; r < 4; ++r) {
          float e = __builtin_amdgcn_exp2f(acc[i][j][r]);
          rs[i][r] += e;
          cs[j] += e;
        }
  } else {
    #pragma unroll
    for (int i = 0; i < 8; ++i)
      #pragma unroll
      for (int j = 0; j < 4; ++j) {
        int gcol = col0 + wc * 64 + j * 16 + m16;
        #pragma unroll
        for (int r = 0; r < 4; ++r) {
          int grow = row0 + wr * 128 + i * 16 + quad * 4 + r;
          float e =
              (grow == gcol) ? 0.f : __builtin_amdgcn_exp2f(acc[i][j][r]);
          rs[i][r] += e;
          cs[j] += e;
        }
      }
  }

  // rowsum: reduce across the 16 column lanes (same quad); 4 wc partials.
  #pragma unroll
  for (int i = 0; i < 8; ++i)
    #pragma unroll
    for (int r = 0; r < 4; ++r) {
      float v = rs[i][r];
      v += __shfl_xor(v, 1, 16);
      v += __shfl_xor(v, 2, 16);
      v += __shfl_xor(v, 4, 16);
      v += __shfl_xor(v, 8, 16);
      if (m16 == 0) rowpart[wc][wr * 128 + i * 16 + quad * 4 + r] = v;
    }
  // colsum: reduce across the 4 quads; 2 wr partials.
  #pragma unroll
  for (int j = 0; j < 4; ++j) {
    float v = cs[j];
    v += __shfl_xor(v, 16, 64);
    v += __shfl_xor(v, 32, 64);
    if (quad == 0) colpart[wr][wc * 64 + j * 16 + m16] = v;
  }
  __syncthreads();

  // denomP slots are 128-row granular (NCB=64 slots): 256-tile (bx,by)
  // covers slot rows {2bx,2bx+1} x cols {2by,2by+1}; use slot index 2*by
  // for rowsums of rows [row0,row0+256) and 2*bx for colsums.
  if (tid < 256) {
    denomP[(size_t)(2 * by) * NROWS + row0 + tid] =
        rowpart[0][tid] + rowpart[1][tid] + rowpart[2][tid] + rowpart[3][tid];
  } else if (bx != by) {
    int c = tid - 256;
    denomP[(size_t)(2 * bx) * NROWS + col0 + c] =
        colpart[0][c] + colpart[1][c];
  }
}

// -------------------- denom slots -> -log; + 2*ln2*pos'; atomic into loss
__global__ __launch_bounds__(256) void reduce_kernel(
    const float* __restrict__ denomP, const float* __restrict__ posv,
    float* __restrict__ out) {
  int tid = threadIdx.x;
  int r = blockIdx.x * 256 + tid;  // 32 blocks cover 8192 rows
  float s = 0.f;
  // 256-tiles write only even slots (2*by for by in 0..31) -> stride 2.
  #pragma unroll 8
  for (int b = 0; b < NCB; b += 2) s += denomP[(size_t)b * NROWS + r];
  float v = -logf(s);
  // posv = 2*sim/ln2; need 4*sim (rows r and r+NHALF) = 2*ln2*posv
  if (r < NHALF) v += 1.38629436112f * posv[r];
  #pragma unroll
  for (int off = 32; off; off >>= 1) v += __shfl_down(v, off, 64);
  __shared__ float s4[4];
  if ((tid & 63) == 0) s4[tid >> 6] = v;
  __syncthreads();
  if (tid == 0)
    atomicAdd(out, (s4[0] + s4[1] + s4[2] + s4[3]) * (1.0f / 8192.0f));
}

extern "C" void kernel_launch(void* const* d_in, const int* in_sizes, int n_in,
                              void* d_out, int out_size, void* d_ws,
                              size_t ws_size, hipStream_t stream) {
  const float* emb_i = (const float*)d_in[0];
  const float* emb_j = (const float*)d_in[1];
  unsigned short* zbF = (unsigned short*)d_ws;           // 4 MB (frag layout)
  float* denomP = (float*)(zbF + (size_t)NROWS * DIM);   // 64*8192 f32 (2 MB)
  float* posv = denomP + (size_t)NCB * NROWS;            // 4096 f32
  float* out = (float*)d_out;

  normalize_kernel<<<NROWS / 16, 256, 0, stream>>>(emb_i, emb_j, zbF, out);
  denom_kernel<<<NTRIT, 512, 0, stream>>>(zbF, denomP, posv);
  reduce_kernel<<<NROWS / 256, 256, 0, stream>>>(denomP, posv, out);
}